// Round 4
// baseline (382.993 us; speedup 1.0000x reference)
//
#include <hip/hip_runtime.h>

// LSTM: B=1024, T=128, H=256, C=10.
// Round 4: single-CU groups (64 blocks x 512 thr). Wh int8 fragments pinned in
// AGPRs via empty inline-asm "+a" (gfx950 unified VGPR/AGPR file; MFMA consumes
// AGPR B-operands directly). h via LDS double buffer, 1 barrier/step. h carried
// as hi/lo residual int8 pair: h ~= hq/127 + lq/(127*254)  (two i8 MFMA chains).

#define TSTEPS  128
#define HDIM    256
#define NCLS    10
#define BB      16          // batch rows per group
#define NBLOCKS 64
#define NTHR    512

// LDS strides
#define XSTR    132         // floats per x row
#define HSTR    272         // bytes per h row (16B-aligned; 4-bank row skew)
#define HBUF    (BB * HSTR) // per parity
#define PSTR    260         // floats per proj row

typedef char  i8x16 __attribute__((ext_vector_type(16)));
typedef int   i32x4 __attribute__((ext_vector_type(4)));

#define L2E     1.4426950408889634f
#define MGC     (-2.0f * L2E)                 // tanh argument scale
#define SMG     (-2.0f * L2E / 16129.0f)      // hi-acc -> zs scale, tanh gate
#define SMS     (-1.0f * L2E / 16129.0f)      // hi-acc -> zs scale, sigmoid gates
#define SMG2    (SMG / 254.0f)                // lo-acc -> zs scale, tanh gate
#define SMS2    (SMS / 254.0f)                // lo-acc -> zs scale, sigmoid gates

static __device__ __forceinline__ float rcpf(float x) {
    return __builtin_amdgcn_rcpf(x);
}
static __device__ __forceinline__ float exp2f_fast(float x) {
    return __builtin_amdgcn_exp2f(x);
}

// ---------------- pre-kernel: quantize + transpose Wh to int8 [gate][unit][k] ----
__global__ __launch_bounds__(64)
void pack_w(const float* __restrict__ wg, const float* __restrict__ wi,
            const float* __restrict__ wf, const float* __restrict__ wo,
            signed char* __restrict__ wq8)
{
    const int b = blockIdx.x;            // 0..1023
    const int q = b >> 8;                // gate
    const int u = b & 255;               // unit (column)
    const float* wp = (q == 0) ? wg : (q == 1) ? wi : (q == 2) ? wf : wo;
    const int t  = threadIdx.x;          // 0..63
    const int k0 = t * 4;
    unsigned int pk = 0;
#pragma unroll
    for (int i = 0; i < 4; ++i) {
        const float v = wp[(k0 + i) * HDIM + u];
        int qv = __float2int_rn(v * 127.0f);
        qv = (qv > 127) ? 127 : ((qv < -127) ? -127 : qv);
        pk |= ((unsigned int)qv & 255u) << (8 * i);
    }
    *(unsigned int*)(wq8 + ((size_t)(q * 256 + u) * 256 + k0)) = pk;
}

// ---------------- main persistent kernel ----------------------------------------
__global__ __launch_bounds__(NTHR, 2)
void lstm_lds(const float* __restrict__ x,
              const float* __restrict__ w_gx, const float* __restrict__ w_ix,
              const float* __restrict__ w_fx, const float* __restrict__ w_ox,
              const float* __restrict__ b_g,  const float* __restrict__ b_i,
              const float* __restrict__ b_f,  const float* __restrict__ b_o,
              const float* __restrict__ w_ph, const float* __restrict__ b_p,
              const signed char* __restrict__ wq8,
              float* __restrict__ out)
{
    const int g    = blockIdx.x;
    const int tid  = threadIdx.x;
    const int w    = tid >> 6;           // wave 0..7
    const int lane = tid & 63;
    const int l16  = lane & 15;
    const int lq   = lane >> 4;          // 0..3

    __shared__ float        x_lds[BB * XSTR];
    __shared__ signed char  h_hi[2 * HBUF];
    __shared__ signed char  h_lo[2 * HBUF];
    __shared__ float        proj[BB * PSTR];

    // x tile (16 rows x 128 steps)
    {
        const float* xs = x + (size_t)g * BB * TSTEPS;
        for (int i = tid; i < BB * TSTEPS; i += NTHR) {
            const int r = i >> 7, tt = i & 127;
            x_lds[r * XSTR + tt] = xs[i];
        }
    }

    // ---- int8 B-fragments, PINNED IN AGPRs -------------------------------------
    // wave w owns units u = w*32 + ut*16 + l16 (ut=0,1), all 4 gates.
    // fragment element e of lane (l16,lq), chunk kk: B[k = kk*64+lq*16+e][u]
    i32x4 wa[4][2][4];
#pragma unroll
    for (int q = 0; q < 4; ++q)
#pragma unroll
        for (int ut = 0; ut < 2; ++ut) {
            const int u = w * 32 + ut * 16 + l16;
#pragma unroll
            for (int kk = 0; kk < 4; ++kk) {
                const signed char* p = wq8 + ((size_t)(q * 256 + u) * 256)
                                           + kk * 64 + lq * 16;
                i32x4 v = __builtin_bit_cast(i32x4, *(const i8x16*)p);
                asm volatile("" : "+a"(v));   // opaque def: lives in AGPR, no remat
                wa[q][ut][kk] = v;
            }
        }

    const float* const wxp[4] = {w_gx, w_ix, w_fx, w_ox};
    const float* const bbp[4] = {b_g, b_i, b_f, b_o};
    float wxm[4][2], bm[4][2];
#pragma unroll
    for (int q = 0; q < 4; ++q)
#pragma unroll
        for (int ut = 0; ut < 2; ++ut) {
            const int u = w * 32 + ut * 16 + l16;
            const float m = (q == 0) ? MGC : (-L2E);
            wxm[q][ut] = wxp[q][u] * m;
            bm[q][ut]  = bbp[q][u] * m;
        }

    float c[2][4] = {{0.f,0.f,0.f,0.f},{0.f,0.f,0.f,0.f}};

    __syncthreads();

    for (int t = 0; t < TSTEPS; ++t) {
        i8x16 ah[4], al[4];
        if (t > 0) {
            const signed char* hs_hi = h_hi + (t & 1) * HBUF + l16 * HSTR;
            const signed char* hs_lo = h_lo + (t & 1) * HBUF + l16 * HSTR;
#pragma unroll
            for (int kk = 0; kk < 4; ++kk) {
                ah[kk] = *(const i8x16*)(hs_hi + kk * 64 + lq * 16);
                al[kk] = *(const i8x16*)(hs_lo + kk * 64 + lq * 16);
            }
        }

        const int p1 = (t + 1) & 1;
        signed char* hd_hi = h_hi + p1 * HBUF;
        signed char* hd_lo = h_lo + p1 * HBUF;

#pragma unroll
        for (int ut = 0; ut < 2; ++ut) {
            i32x4 a1[4] = {{0,0,0,0},{0,0,0,0},{0,0,0,0},{0,0,0,0}};
            i32x4 a2[4] = {{0,0,0,0},{0,0,0,0},{0,0,0,0},{0,0,0,0}};
            if (t > 0) {
#pragma unroll
                for (int kk = 0; kk < 4; ++kk)
#pragma unroll
                    for (int q = 0; q < 4; ++q) {
                        a1[q] = __builtin_amdgcn_mfma_i32_16x16x64_i8(
                                    __builtin_bit_cast(i32x4, ah[kk]),
                                    wa[q][ut][kk], a1[q], 0, 0, 0);
                        a2[q] = __builtin_amdgcn_mfma_i32_16x16x64_i8(
                                    __builtin_bit_cast(i32x4, al[kk]),
                                    wa[q][ut][kk], a2[q], 0, 0, 0);
                    }
            }
            const int u = w * 32 + ut * 16 + l16;
#pragma unroll
            for (int j = 0; j < 4; ++j) {
                const int   row = lq * 4 + j;
                const float xv  = x_lds[row * XSTR + t];
                // zs = a1*SM + a2*(SM/254) + (xv*wxm + bm)
                const float xb0 = __builtin_fmaf(xv, wxm[0][ut], bm[0][ut]);
                const float xb1 = __builtin_fmaf(xv, wxm[1][ut], bm[1][ut]);
                const float xb2 = __builtin_fmaf(xv, wxm[2][ut], bm[2][ut]);
                const float xb3 = __builtin_fmaf(xv, wxm[3][ut], bm[3][ut]);
                const float zs0 = __builtin_fmaf((float)a1[0][j], SMG,
                                  __builtin_fmaf((float)a2[0][j], SMG2, xb0));
                const float zs1 = __builtin_fmaf((float)a1[1][j], SMS,
                                  __builtin_fmaf((float)a2[1][j], SMS2, xb1));
                const float zs2 = __builtin_fmaf((float)a1[2][j], SMS,
                                  __builtin_fmaf((float)a2[2][j], SMS2, xb2));
                const float zs3 = __builtin_fmaf((float)a1[3][j], SMS,
                                  __builtin_fmaf((float)a2[3][j], SMS2, xb3));
                const float gg = 2.0f * rcpf(1.0f + exp2f_fast(zs0)) - 1.0f;  // tanh
                const float ii = rcpf(1.0f + exp2f_fast(zs1));                // sigmoid
                const float ff = rcpf(1.0f + exp2f_fast(zs2));
                const float oo = rcpf(1.0f + exp2f_fast(zs3));
                const float cc = __builtin_fmaf(c[ut][j], ff, gg * ii);
                c[ut][j] = cc;
                const float tc = 2.0f * rcpf(1.0f + exp2f_fast(cc * MGC)) - 1.0f;
                const float hh = tc * oo;
                // hi/lo residual quantization: h ~= hq/127 + lqv/(127*254)
                const float fq  = hh * 127.0f;
                const int   hq  = __float2int_rn(fq);
                const float er  = fq - (float)hq;
                const int   lqv = __float2int_rn(er * 254.0f);
                hd_hi[row * HSTR + u] = (signed char)hq;
                hd_lo[row * HSTR + u] = (signed char)lqv;
                if (t == TSTEPS - 1) proj[row * PSTR + u] = hh;
            }
        }
        __syncthreads();
    }

    // ---- final projection: out[g*16 + r][cls], 16x10 ----------------------------
    if (tid < BB * NCLS) {
        const int r = tid / NCLS, cls = tid - r * NCLS;
        float a = b_p[cls];
#pragma unroll 8
        for (int u = 0; u < HDIM; ++u) {
            a = __builtin_fmaf(proj[r * PSTR + u], w_ph[u * NCLS + cls], a);
        }
        out[(size_t)(g * BB + r) * NCLS + cls] = a;
    }
}

extern "C" void kernel_launch(void* const* d_in, const int* in_sizes, int n_in,
                              void* d_out, int out_size, void* d_ws, size_t ws_size,
                              hipStream_t stream)
{
    const float* x    = (const float*)d_in[0];
    const float* w_gx = (const float*)d_in[1];
    const float* w_ix = (const float*)d_in[2];
    const float* w_fx = (const float*)d_in[3];
    const float* w_ox = (const float*)d_in[4];
    const float* w_gh = (const float*)d_in[5];
    const float* w_ih = (const float*)d_in[6];
    const float* w_fh = (const float*)d_in[7];
    const float* w_oh = (const float*)d_in[8];
    const float* b_g  = (const float*)d_in[9];
    const float* b_i  = (const float*)d_in[10];
    const float* b_f  = (const float*)d_in[11];
    const float* b_o  = (const float*)d_in[12];
    const float* w_ph = (const float*)d_in[13];
    const float* b_p  = (const float*)d_in[14];

    signed char* wq8 = (signed char*)d_ws;   // 4*256*256 = 256 KB

    hipLaunchKernelGGL(pack_w, dim3(1024), dim3(64), 0, stream,
                       w_gh, w_ih, w_fh, w_oh, wq8);

    hipLaunchKernelGGL(lstm_lds, dim3(NBLOCKS), dim3(NTHR), 0, stream,
                       x, w_gx, w_ix, w_fx, w_ox,
                       b_g, b_i, b_f, b_o, w_ph, b_p,
                       wq8, (float*)d_out);
}

// Round 5
// 264.183 us; speedup vs baseline: 1.4497x; 1.4497x over previous
//
#include <hip/hip_runtime.h>

// LSTM: B=1024, T=128, H=256, C=10.
// Round 5: 256 blocks x 512 thr, BB=4 batch rows per block (full chip).
// Wh int8 fragments pinned in AGPRs (volatile asm def) and consumed by inline-asm
// v_mfma_i32_16x16x64_i8 with "a" constraint -> truly register-resident, no copies.
// h via LDS double buffer (1 barrier/step). hi/lo residual int8 h (two MFMA chains).
// Epilogue redistributed across all 64 lanes via per-wave LDS bounce buffer.

#define TSTEPS  128
#define HDIM    256
#define NCLS    10
#define BB      4
#define NBLOCKS 256
#define NTHR    512

#define XSTR    132                 // floats per x row
#define HSTR    272                 // bytes per h row (16B aligned)
#define HROWS   BB
#define PSTR    260

typedef char  i8x16 __attribute__((ext_vector_type(16)));
typedef int   i32x4 __attribute__((ext_vector_type(4)));

#define L2E     1.4426950408889634f
#define MGC     (-2.0f * L2E)
#define SMG     (-2.0f * L2E / 16129.0f)
#define SMS     (-1.0f * L2E / 16129.0f)
#define SMG2    (SMG / 254.0f)
#define SMS2    (SMS / 254.0f)

static __device__ __forceinline__ float rcpf(float x) { return __builtin_amdgcn_rcpf(x); }
static __device__ __forceinline__ float exp2f_fast(float x) { return __builtin_amdgcn_exp2f(x); }

#define MFMA_I8(ACC, A, B) \
    asm("v_mfma_i32_16x16x64_i8 %0, %1, %2, %0" : "+v"(ACC) : "v"(A), "a"(B))

// ---------------- pre-kernel: quantize + transpose Wh to int8 [gate][unit][k] ----
__global__ __launch_bounds__(64)
void pack_w(const float* __restrict__ wg, const float* __restrict__ wi,
            const float* __restrict__ wf, const float* __restrict__ wo,
            signed char* __restrict__ wq8)
{
    const int b = blockIdx.x;            // 0..1023
    const int q = b >> 8;                // gate
    const int u = b & 255;               // unit (column)
    const float* wp = (q == 0) ? wg : (q == 1) ? wi : (q == 2) ? wf : wo;
    const int t  = threadIdx.x;          // 0..63
    const int k0 = t * 4;
    unsigned int pk = 0;
#pragma unroll
    for (int i = 0; i < 4; ++i) {
        const float v = wp[(k0 + i) * HDIM + u];
        int qv = __float2int_rn(v * 127.0f);
        qv = (qv > 127) ? 127 : ((qv < -127) ? -127 : qv);
        pk |= ((unsigned int)qv & 255u) << (8 * i);
    }
    *(unsigned int*)(wq8 + ((size_t)(q * 256 + u) * 256 + k0)) = pk;
}

// ---------------- main persistent kernel ----------------------------------------
__global__ __launch_bounds__(NTHR, 2)
void lstm_full(const float* __restrict__ x,
               const float* __restrict__ w_gx, const float* __restrict__ w_ix,
               const float* __restrict__ w_fx, const float* __restrict__ w_ox,
               const float* __restrict__ b_g,  const float* __restrict__ b_i,
               const float* __restrict__ b_f,  const float* __restrict__ b_o,
               const float* __restrict__ w_ph, const float* __restrict__ b_p,
               const signed char* __restrict__ wq8,
               float* __restrict__ out)
{
    const int g    = blockIdx.x;         // 0..255, batch rows [g*4, g*4+4)
    const int tid  = threadIdx.x;
    const int w    = tid >> 6;           // wave 0..7
    const int lane = tid & 63;
    const int l16  = lane & 15;
    const int lq   = lane >> 4;          // 0..3

    __shared__ float        x_lds[BB * XSTR];                 // 2.1 KB
    __shared__ signed char  h_hi[2][HROWS * HSTR];            // 2.2 KB
    __shared__ signed char  h_lo[2][HROWS * HSTR];            // 2.2 KB
    __shared__ int          bounce[8][1024];                  // 32 KB (4KB/wave)
    __shared__ float        proj[BB * PSTR];                  // 4.2 KB

    {   // x tile: 4 rows x 128 steps
        const float* xs = x + (size_t)g * BB * TSTEPS;
        for (int i = tid; i < BB * TSTEPS; i += NTHR)
            x_lds[(i >> 7) * XSTR + (i & 127)] = xs[i];
    }

    // ---- int8 B-fragments, pinned in AGPRs (volatile def: cannot sink/remat) ----
    // wave w owns units u = w*32 + ut*16 + l16 (ut=0,1), all 4 gates.
    // element e of lane (l16,lq), chunk kk: B[k = kk*64+lq*16+e][u]
    i32x4 wa[4][2][4];
#pragma unroll
    for (int q = 0; q < 4; ++q)
#pragma unroll
        for (int ut = 0; ut < 2; ++ut) {
            const int u = w * 32 + ut * 16 + l16;
#pragma unroll
            for (int kk = 0; kk < 4; ++kk) {
                const signed char* p = wq8 + ((size_t)(q * 256 + u) * 256)
                                           + kk * 64 + lq * 16;
                i32x4 v = __builtin_bit_cast(i32x4, *(const i8x16*)p);
                asm volatile("" : "+a"(v));
                wa[q][ut][kk] = v;
            }
        }

    const float* const wxp[4] = {w_gx, w_ix, w_fx, w_ox};
    const float* const bbp[4] = {b_g, b_i, b_f, b_o};
    float wxm[4][2], bm[4][2];
#pragma unroll
    for (int q = 0; q < 4; ++q)
#pragma unroll
        for (int ut = 0; ut < 2; ++ut) {
            const int u = w * 32 + ut * 16 + l16;   // depends only on l16 -> also
            const float m = (q == 0) ? MGC : (-L2E); // correct for epilogue lane map
            wxm[q][ut] = wxp[q][u] * m;
            bm[q][ut]  = bbp[q][u] * m;
        }

    float c[2] = {0.f, 0.f};             // cell state: lane owns (row=lane>>4, ut)

    __syncthreads();

    for (int t = 0; t < TSTEPS; ++t) {
        // A fragments: rows l16&3 (lanes 4..15 broadcast rows 0..3; D rows 4..15 junk)
        i32x4 ah[4], al[4];
        if (t > 0) {
            const signed char* hs_hi = &h_hi[t & 1][(l16 & 3) * HSTR];
            const signed char* hs_lo = &h_lo[t & 1][(l16 & 3) * HSTR];
#pragma unroll
            for (int kk = 0; kk < 4; ++kk) {
                ah[kk] = *(const i32x4*)(hs_hi + kk * 64 + lq * 16);
                al[kk] = *(const i32x4*)(hs_lo + kk * 64 + lq * 16);
            }
        }

#pragma unroll
        for (int ut = 0; ut < 2; ++ut) {
            i32x4 a1[4] = {{0,0,0,0},{0,0,0,0},{0,0,0,0},{0,0,0,0}};
            i32x4 a2[4] = {{0,0,0,0},{0,0,0,0},{0,0,0,0},{0,0,0,0}};
            if (t > 0) {
#pragma unroll
                for (int kk = 0; kk < 4; ++kk)
#pragma unroll
                    for (int q = 0; q < 4; ++q) {
                        MFMA_I8(a1[q], ah[kk], wa[q][ut][kk]);
                        MFMA_I8(a2[q], al[kk], wa[q][ut][kk]);
                    }
            }
            // writer: lq==0 lanes hold valid D rows j=0..3 for unit l16.
            // layout slot = ((ut*2+chain)*4+q)*16 + l16 ; 16B per slot (j fastest)
            if (lq == 0) {
                i32x4* bw = (i32x4*)bounce[w];
#pragma unroll
                for (int q = 0; q < 4; ++q) {
                    bw[((ut * 2 + 0) * 4 + q) * 16 + l16] = a1[q];
                    bw[((ut * 2 + 1) * 4 + q) * 16 + l16] = a2[q];
                }
            }
        }

        // reader: all 64 lanes, 2 outputs each (row = lane>>4, unit l16-mapped)
        const int   row = lane >> 4;
        const float xv  = x_lds[row * XSTR + t];
        signed char* hd_hi = &h_hi[(t + 1) & 1][0];
        signed char* hd_lo = &h_lo[(t + 1) & 1][0];
#pragma unroll
        for (int ut = 0; ut < 2; ++ut) {
            const int* br = bounce[w];
            float zs[4];
#pragma unroll
            for (int q = 0; q < 4; ++q) {
                const int hi = br[(((ut * 2 + 0) * 4 + q) * 16 + l16) * 4 + row];
                const int lo = br[(((ut * 2 + 1) * 4 + q) * 16 + l16) * 4 + row];
                const float sm  = (q == 0) ? SMG  : SMS;
                const float sm2 = (q == 0) ? SMG2 : SMS2;
                zs[q] = __builtin_fmaf((float)hi, sm,
                        __builtin_fmaf((float)lo, sm2,
                        __builtin_fmaf(xv, wxm[q][ut], bm[q][ut])));
            }
            const float gg = 2.0f * rcpf(1.0f + exp2f_fast(zs[0])) - 1.0f; // tanh
            const float ii = rcpf(1.0f + exp2f_fast(zs[1]));
            const float ff = rcpf(1.0f + exp2f_fast(zs[2]));
            const float oo = rcpf(1.0f + exp2f_fast(zs[3]));
            const float cc = __builtin_fmaf(c[ut], ff, gg * ii);
            c[ut] = cc;
            const float tc = 2.0f * rcpf(1.0f + exp2f_fast(cc * MGC)) - 1.0f;
            const float hh = tc * oo;
            // hi/lo residual quantization: h ~= hq/127 + lqv/(127*254)
            const float fq  = hh * 127.0f;
            const int   hq  = __float2int_rn(fq);
            const float er  = fq - (float)hq;
            const int   lqv = __float2int_rn(er * 254.0f);
            const int   u   = w * 32 + ut * 16 + l16;
            hd_hi[row * HSTR + u] = (signed char)hq;
            hd_lo[row * HSTR + u] = (signed char)lqv;
            if (t == TSTEPS - 1) proj[row * PSTR + u] = hh;
        }
        __syncthreads();
    }

    // ---- final projection: out[g*4 + r][cls], 4x10 -------------------------------
    if (tid < BB * NCLS) {
        const int r = tid / NCLS, cls = tid - r * NCLS;
        float a = b_p[cls];
#pragma unroll 8
        for (int u = 0; u < HDIM; ++u)
            a = __builtin_fmaf(proj[r * PSTR + u], w_ph[u * NCLS + cls], a);
        out[(size_t)(g * BB + r) * NCLS + cls] = a;
    }
}

extern "C" void kernel_launch(void* const* d_in, const int* in_sizes, int n_in,
                              void* d_out, int out_size, void* d_ws, size_t ws_size,
                              hipStream_t stream)
{
    const float* x    = (const float*)d_in[0];
    const float* w_gx = (const float*)d_in[1];
    const float* w_ix = (const float*)d_in[2];
    const float* w_fx = (const float*)d_in[3];
    const float* w_ox = (const float*)d_in[4];
    const float* w_gh = (const float*)d_in[5];
    const float* w_ih = (const float*)d_in[6];
    const float* w_fh = (const float*)d_in[7];
    const float* w_oh = (const float*)d_in[8];
    const float* b_g  = (const float*)d_in[9];
    const float* b_i  = (const float*)d_in[10];
    const float* b_f  = (const float*)d_in[11];
    const float* b_o  = (const float*)d_in[12];
    const float* w_ph = (const float*)d_in[13];
    const float* b_p  = (const float*)d_in[14];

    signed char* wq8 = (signed char*)d_ws;   // 4*256*256 = 256 KB

    hipLaunchKernelGGL(pack_w, dim3(1024), dim3(64), 0, stream,
                       w_gh, w_ih, w_fh, w_oh, wq8);

    hipLaunchKernelGGL(lstm_full, dim3(NBLOCKS), dim3(NTHR), 0, stream,
                       x, w_gx, w_ix, w_fx, w_ox,
                       b_g, b_i, b_f, b_o, w_ph, b_p,
                       wq8, (float*)d_out);
}

// Round 6
// 156.151 us; speedup vs baseline: 2.4527x; 1.6918x over previous
//
#include <hip/hip_runtime.h>

// LSTM: B=1024, T=128, H=256, C=10.
// Round 6: 256 blocks x 512 thr, BB=4 batch rows per block (full chip).
// Wh int8 in AGPRs (volatile asm pin) consumed by inline-asm v_mfma_i32_16x16x64_i8
// with "a" B-operand. h carried as SINGLE int8 (err <= 1/254 ~= bf16-grade, which
// passed with absmax 0.0 in rounds 1-2). One MFMA chain: 256 MFMA/CU/step.
// h via LDS double buffer (1 barrier/step); epilogue redistributed to all 64
// lanes via 2KB/wave LDS bounce buffer. HSTR=320 kills the 4-way h-read conflict.

#define TSTEPS  128
#define HDIM    256
#define NCLS    10
#define BB      4
#define NBLOCKS 256
#define NTHR    512

#define XSTR    132                 // floats per x row
#define HSTR    320                 // bytes per h row: bank = (16r+4lq)%32 -> 2-way
#define PSTR    260

typedef char  i8x16 __attribute__((ext_vector_type(16)));
typedef int   i32x4 __attribute__((ext_vector_type(4)));

#define L2E     1.4426950408889634f
#define MGC     (-2.0f * L2E)
#define SMG     (-2.0f * L2E / 16129.0f)   // acc scale, tanh gate (1/(127*127))
#define SMS     (-1.0f * L2E / 16129.0f)   // acc scale, sigmoid gates

static __device__ __forceinline__ float rcpf(float x) { return __builtin_amdgcn_rcpf(x); }
static __device__ __forceinline__ float exp2f_fast(float x) { return __builtin_amdgcn_exp2f(x); }

#define MFMA_I8(ACC, A, B) \
    asm("v_mfma_i32_16x16x64_i8 %0, %1, %2, %0" : "+v"(ACC) : "v"(A), "a"(B))

// ---------------- pre-kernel: quantize + transpose Wh to int8 [gate][unit][k] ----
__global__ __launch_bounds__(64)
void pack_w(const float* __restrict__ wg, const float* __restrict__ wi,
            const float* __restrict__ wf, const float* __restrict__ wo,
            signed char* __restrict__ wq8)
{
    const int b = blockIdx.x;            // 0..1023
    const int q = b >> 8;                // gate
    const int u = b & 255;               // unit (column)
    const float* wp = (q == 0) ? wg : (q == 1) ? wi : (q == 2) ? wf : wo;
    const int t  = threadIdx.x;          // 0..63
    const int k0 = t * 4;
    unsigned int pk = 0;
#pragma unroll
    for (int i = 0; i < 4; ++i) {
        const float v = wp[(k0 + i) * HDIM + u];
        int qv = __float2int_rn(v * 127.0f);
        qv = (qv > 127) ? 127 : ((qv < -127) ? -127 : qv);
        pk |= ((unsigned int)qv & 255u) << (8 * i);
    }
    *(unsigned int*)(wq8 + ((size_t)(q * 256 + u) * 256 + k0)) = pk;
}

// ---------------- main persistent kernel ----------------------------------------
__global__ __launch_bounds__(NTHR, 2)
void lstm_full(const float* __restrict__ x,
               const float* __restrict__ w_gx, const float* __restrict__ w_ix,
               const float* __restrict__ w_fx, const float* __restrict__ w_ox,
               const float* __restrict__ b_g,  const float* __restrict__ b_i,
               const float* __restrict__ b_f,  const float* __restrict__ b_o,
               const float* __restrict__ w_ph, const float* __restrict__ b_p,
               const signed char* __restrict__ wq8,
               float* __restrict__ out)
{
    const int g    = blockIdx.x;         // 0..255, batch rows [g*4, g*4+4)
    const int tid  = threadIdx.x;
    const int w    = tid >> 6;           // wave 0..7
    const int lane = tid & 63;
    const int l16  = lane & 15;
    const int lq   = lane >> 4;          // 0..3

    __shared__ float        x_lds[BB * XSTR];           // 2.1 KB
    __shared__ signed char  h_q[2][BB * HSTR];          // 2.5 KB
    __shared__ int          bounce[8][512];             // 16 KB (2KB/wave)
    __shared__ float        proj[BB * PSTR];            // 4.2 KB

    {   // x tile: 4 rows x 128 steps
        const float* xs = x + (size_t)g * BB * TSTEPS;
        for (int i = tid; i < BB * TSTEPS; i += NTHR)
            x_lds[(i >> 7) * XSTR + (i & 127)] = xs[i];
    }

    // ---- int8 B-fragments, pinned in AGPRs (volatile def: no sink/remat) --------
    // wave w owns units u = w*32 + ut*16 + l16 (ut=0,1), all 4 gates.
    // element e of lane (l16,lq), chunk kk: B[k = kk*64+lq*16+e][u]
    i32x4 wa[4][2][4];
#pragma unroll
    for (int q = 0; q < 4; ++q)
#pragma unroll
        for (int ut = 0; ut < 2; ++ut) {
            const int u = w * 32 + ut * 16 + l16;
#pragma unroll
            for (int kk = 0; kk < 4; ++kk) {
                const signed char* p = wq8 + ((size_t)(q * 256 + u) * 256)
                                           + kk * 64 + lq * 16;
                i32x4 v = __builtin_bit_cast(i32x4, *(const i8x16*)p);
                asm volatile("" : "+a"(v));
                wa[q][ut][kk] = v;
            }
        }

    const float* const wxp[4] = {w_gx, w_ix, w_fx, w_ox};
    const float* const bbp[4] = {b_g, b_i, b_f, b_o};
    float wxm[4][2], bm[4][2];
#pragma unroll
    for (int q = 0; q < 4; ++q)
#pragma unroll
        for (int ut = 0; ut < 2; ++ut) {
            const int u = w * 32 + ut * 16 + l16;    // l16-dependent only: valid for
            const float m = (q == 0) ? MGC : (-L2E); // both MFMA and epilogue maps
            wxm[q][ut] = wxp[q][u] * m;
            bm[q][ut]  = bbp[q][u] * m;
        }

    float c[2] = {0.f, 0.f};             // cell state: lane owns (row=lane>>4, ut)

    __syncthreads();

    for (int t = 0; t < TSTEPS; ++t) {
        // A fragments: rows l16&3 (lanes 4..15 broadcast; D rows 4..15 junk)
        i32x4 ah[4];
        if (t > 0) {
            const signed char* hs = &h_q[t & 1][(l16 & 3) * HSTR];
#pragma unroll
            for (int kk = 0; kk < 4; ++kk)
                ah[kk] = *(const i32x4*)(hs + kk * 64 + lq * 16);
        }

#pragma unroll
        for (int ut = 0; ut < 2; ++ut) {
            i32x4 a1[4] = {{0,0,0,0},{0,0,0,0},{0,0,0,0},{0,0,0,0}};
            if (t > 0) {
#pragma unroll
                for (int kk = 0; kk < 4; ++kk)
#pragma unroll
                    for (int q = 0; q < 4; ++q)
                        MFMA_I8(a1[q], ah[kk], wa[q][ut][kk]);
            }
            // writer: lq==0 lanes hold valid D rows j=0..3 for unit l16.
            // slot = (ut*4+q)*16 + l16 ; 16B per slot (j fastest)
            if (lq == 0) {
                i32x4* bw = (i32x4*)bounce[w];
#pragma unroll
                for (int q = 0; q < 4; ++q)
                    bw[(ut * 4 + q) * 16 + l16] = a1[q];
            }
        }

        // reader: all 64 lanes, 2 outputs each (row = lane>>4, unit w*32+ut*16+l16)
        const int   row = lane >> 4;
        const float xv  = x_lds[row * XSTR + t];
        signed char* hd = &h_q[(t + 1) & 1][0];
#pragma unroll
        for (int ut = 0; ut < 2; ++ut) {
            const int* br = bounce[w];
            float zs[4];
#pragma unroll
            for (int q = 0; q < 4; ++q) {
                const int hi = br[((ut * 4 + q) * 16 + l16) * 4 + row];
                const float sm = (q == 0) ? SMG : SMS;
                zs[q] = __builtin_fmaf((float)hi, sm,
                        __builtin_fmaf(xv, wxm[q][ut], bm[q][ut]));
            }
            const float gg = 2.0f * rcpf(1.0f + exp2f_fast(zs[0])) - 1.0f; // tanh
            const float ii = rcpf(1.0f + exp2f_fast(zs[1]));
            const float ff = rcpf(1.0f + exp2f_fast(zs[2]));
            const float oo = rcpf(1.0f + exp2f_fast(zs[3]));
            const float cc = __builtin_fmaf(c[ut], ff, gg * ii);
            c[ut] = cc;
            const float tc = 2.0f * rcpf(1.0f + exp2f_fast(cc * MGC)) - 1.0f;
            const float hh = tc * oo;
            // single int8 quantization: h ~= hq/127, |err| <= 1/254 (bf16-grade)
            const int   hq = __float2int_rn(hh * 127.0f);
            const int   u  = w * 32 + ut * 16 + l16;
            hd[row * HSTR + u] = (signed char)hq;
            if (t == TSTEPS - 1) proj[row * PSTR + u] = hh;
        }
        __syncthreads();
    }

    // ---- final projection: out[g*4 + r][cls], 4x10 -------------------------------
    if (tid < BB * NCLS) {
        const int r = tid / NCLS, cls = tid - r * NCLS;
        float a = b_p[cls];
#pragma unroll 8
        for (int u = 0; u < HDIM; ++u)
            a = __builtin_fmaf(proj[r * PSTR + u], w_ph[u * NCLS + cls], a);
        out[(size_t)(g * BB + r) * NCLS + cls] = a;
    }
}

extern "C" void kernel_launch(void* const* d_in, const int* in_sizes, int n_in,
                              void* d_out, int out_size, void* d_ws, size_t ws_size,
                              hipStream_t stream)
{
    const float* x    = (const float*)d_in[0];
    const float* w_gx = (const float*)d_in[1];
    const float* w_ix = (const float*)d_in[2];
    const float* w_fx = (const float*)d_in[3];
    const float* w_ox = (const float*)d_in[4];
    const float* w_gh = (const float*)d_in[5];
    const float* w_ih = (const float*)d_in[6];
    const float* w_fh = (const float*)d_in[7];
    const float* w_oh = (const float*)d_in[8];
    const float* b_g  = (const float*)d_in[9];
    const float* b_i  = (const float*)d_in[10];
    const float* b_f  = (const float*)d_in[11];
    const float* b_o  = (const float*)d_in[12];
    const float* w_ph = (const float*)d_in[13];
    const float* b_p  = (const float*)d_in[14];

    signed char* wq8 = (signed char*)d_ws;   // 4*256*256 = 256 KB

    hipLaunchKernelGGL(pack_w, dim3(1024), dim3(64), 0, stream,
                       w_gh, w_ih, w_fh, w_oh, wq8);

    hipLaunchKernelGGL(lstm_full, dim3(NBLOCKS), dim3(NTHR), 0, stream,
                       x, w_gx, w_ix, w_fx, w_ox,
                       b_g, b_i, b_f, b_o, w_ph, b_p,
                       wq8, (float*)d_out);
}

// Round 7
// 132.182 us; speedup vs baseline: 2.8975x; 1.1813x over previous
//
#include <hip/hip_runtime.h>

// LSTM: B=1024, T=128, H=256, C=10.
// Round 7: 256 blocks x 512 thr, BB=4. Wh int8 in AGPRs, inline-asm
// v_mfma_i32_16x16x64_i8 ("a" B-operand). Single int8 h (validated, absmax 0.0).
// NEW: no bounce buffer. A broadcasts h rows (l16&3), so D row r = batch row r&3:
// every lq quadrant holds all 4 rows; lane picks j=lq via cndmask selects (pure
// VALU, overlaps with the other ut's MFMA pipe time). 1 barrier/step.

#define TSTEPS  128
#define HDIM    256
#define NCLS    10
#define BB      4
#define NBLOCKS 256
#define NTHR    512

#define XSTR    132                 // floats per x row: bank (4lq+t)%32, conflict-free
#define HSTR    320                 // bytes per h row: 2-way on b128 reads (free)
#define PSTR    260

typedef char  i8x16 __attribute__((ext_vector_type(16)));
typedef int   i32x4 __attribute__((ext_vector_type(4)));

#define L2E     1.4426950408889634f
#define MGC     (-2.0f * L2E)
#define SMG     (-2.0f * L2E / 16129.0f)   // acc scale, tanh gate (1/(127*127))
#define SMS     (-1.0f * L2E / 16129.0f)   // acc scale, sigmoid gates

static __device__ __forceinline__ float rcpf(float x) { return __builtin_amdgcn_rcpf(x); }
static __device__ __forceinline__ float exp2f_fast(float x) { return __builtin_amdgcn_exp2f(x); }

#define MFMA_I8(ACC, A, B) \
    asm("v_mfma_i32_16x16x64_i8 %0, %1, %2, %0" : "+v"(ACC) : "v"(A), "a"(B))

// ---------------- pre-kernel: quantize + transpose Wh to int8 [gate][unit][k] ----
__global__ __launch_bounds__(64)
void pack_w(const float* __restrict__ wg, const float* __restrict__ wi,
            const float* __restrict__ wf, const float* __restrict__ wo,
            signed char* __restrict__ wq8)
{
    const int b = blockIdx.x;            // 0..1023
    const int q = b >> 8;                // gate
    const int u = b & 255;               // unit (column)
    const float* wp = (q == 0) ? wg : (q == 1) ? wi : (q == 2) ? wf : wo;
    const int t  = threadIdx.x;          // 0..63
    const int k0 = t * 4;
    unsigned int pk = 0;
#pragma unroll
    for (int i = 0; i < 4; ++i) {
        const float v = wp[(k0 + i) * HDIM + u];
        int qv = __float2int_rn(v * 127.0f);
        qv = (qv > 127) ? 127 : ((qv < -127) ? -127 : qv);
        pk |= ((unsigned int)qv & 255u) << (8 * i);
    }
    *(unsigned int*)(wq8 + ((size_t)(q * 256 + u) * 256 + k0)) = pk;
}

// ---------------- main persistent kernel ----------------------------------------
__global__ __launch_bounds__(NTHR, 2)
void lstm_full(const float* __restrict__ x,
               const float* __restrict__ w_gx, const float* __restrict__ w_ix,
               const float* __restrict__ w_fx, const float* __restrict__ w_ox,
               const float* __restrict__ b_g,  const float* __restrict__ b_i,
               const float* __restrict__ b_f,  const float* __restrict__ b_o,
               const float* __restrict__ w_ph, const float* __restrict__ b_p,
               const signed char* __restrict__ wq8,
               float* __restrict__ out)
{
    const int g    = blockIdx.x;         // 0..255, batch rows [g*4, g*4+4)
    const int tid  = threadIdx.x;
    const int w    = tid >> 6;           // wave 0..7
    const int lane = tid & 63;
    const int l16  = lane & 15;
    const int lq   = lane >> 4;          // 0..3  == this lane's batch row

    __shared__ float        x_lds[BB * XSTR];           // 2.1 KB
    __shared__ signed char  h_q[2][BB * HSTR];          // 2.5 KB
    __shared__ float        proj[BB * PSTR];            // 4.2 KB

    {   // x tile: 4 rows x 128 steps
        const float* xs = x + (size_t)g * BB * TSTEPS;
        for (int i = tid; i < BB * TSTEPS; i += NTHR)
            x_lds[(i >> 7) * XSTR + (i & 127)] = xs[i];
    }

    // ---- int8 B-fragments, pinned in AGPRs (volatile def: no sink/remat) --------
    // wave w owns units u = w*32 + ut*16 + l16 (ut=0,1), all 4 gates.
    // element e of lane (l16,lq), chunk kk: B[k = kk*64+lq*16+e][u]
    i32x4 wa[4][2][4];
#pragma unroll
    for (int q = 0; q < 4; ++q)
#pragma unroll
        for (int ut = 0; ut < 2; ++ut) {
            const int u = w * 32 + ut * 16 + l16;
#pragma unroll
            for (int kk = 0; kk < 4; ++kk) {
                const signed char* p = wq8 + ((size_t)(q * 256 + u) * 256)
                                           + kk * 64 + lq * 16;
                i32x4 v = __builtin_bit_cast(i32x4, *(const i8x16*)p);
                asm volatile("" : "+a"(v));
                wa[q][ut][kk] = v;
            }
        }

    const float* const wxp[4] = {w_gx, w_ix, w_fx, w_ox};
    const float* const bbp[4] = {b_g, b_i, b_f, b_o};
    float wxm[4][2], bm[4][2];
#pragma unroll
    for (int q = 0; q < 4; ++q)
#pragma unroll
        for (int ut = 0; ut < 2; ++ut) {
            const int u = w * 32 + ut * 16 + l16;    // l16-dependent only
            const float m = (q == 0) ? MGC : (-L2E);
            wxm[q][ut] = wxp[q][u] * m;
            bm[q][ut]  = bbp[q][u] * m;
        }

    float c[2] = {0.f, 0.f};             // cell state: lane owns (row=lq, ut)
    const bool s0 = (lq & 1) != 0;       // select bits for j=lq extraction
    const bool s1 = (lq & 2) != 0;

    __syncthreads();

    for (int t = 0; t < TSTEPS; ++t) {
        // A fragments: rows l16&3 broadcast -> D row r == batch row (r&3)
        i32x4 ah[4];
        if (t > 0) {
            const signed char* hs = &h_q[t & 1][(l16 & 3) * HSTR];
#pragma unroll
            for (int kk = 0; kk < 4; ++kk)
                ah[kk] = *(const i32x4*)(hs + kk * 64 + lq * 16);
        }

        i32x4 a0[4] = {{0,0,0,0},{0,0,0,0},{0,0,0,0},{0,0,0,0}};
        i32x4 a1[4] = {{0,0,0,0},{0,0,0,0},{0,0,0,0},{0,0,0,0}};
        if (t > 0) {
#pragma unroll
            for (int kk = 0; kk < 4; ++kk)
#pragma unroll
                for (int q = 0; q < 4; ++q)
                    MFMA_I8(a0[q], ah[kk], wa[q][0][kk]);
#pragma unroll
            for (int kk = 0; kk < 4; ++kk)
#pragma unroll
                for (int q = 0; q < 4; ++q)
                    MFMA_I8(a1[q], ah[kk], wa[q][1][kk]);
        }

        // epilogue: lane handles (row=lq, unit w*32+ut*16+l16); acc j=lq via selects
        const float xv = x_lds[lq * XSTR + t];
        signed char* hd = &h_q[(t + 1) & 1][0];
#pragma unroll
        for (int ut = 0; ut < 2; ++ut) {
            float zs[4];
#pragma unroll
            for (int q = 0; q < 4; ++q) {
                const i32x4 v = ut ? a1[q] : a0[q];
                const int lo = s0 ? v[1] : v[0];
                const int hi = s0 ? v[3] : v[2];
                const int av = s1 ? hi : lo;
                const float sm = (q == 0) ? SMG : SMS;
                zs[q] = __builtin_fmaf((float)av, sm,
                        __builtin_fmaf(xv, wxm[q][ut], bm[q][ut]));
            }
            const float gg = 2.0f * rcpf(1.0f + exp2f_fast(zs[0])) - 1.0f; // tanh
            const float ii = rcpf(1.0f + exp2f_fast(zs[1]));
            const float ff = rcpf(1.0f + exp2f_fast(zs[2]));
            const float oo = rcpf(1.0f + exp2f_fast(zs[3]));
            const float cc = __builtin_fmaf(c[ut], ff, gg * ii);
            c[ut] = cc;
            const float tc = 2.0f * rcpf(1.0f + exp2f_fast(cc * MGC)) - 1.0f;
            const float hh = tc * oo;
            const int   hq = __float2int_rn(hh * 127.0f);   // |err| <= 1/254
            const int   u  = w * 32 + ut * 16 + l16;
            hd[lq * HSTR + u] = (signed char)hq;
            if (t == TSTEPS - 1) proj[lq * PSTR + u] = hh;
        }
        __syncthreads();
    }

    // ---- final projection: out[g*4 + r][cls], 4x10 -------------------------------
    if (tid < BB * NCLS) {
        const int r = tid / NCLS, cls = tid - r * NCLS;
        float a = b_p[cls];
#pragma unroll 8
        for (int u = 0; u < HDIM; ++u)
            a = __builtin_fmaf(proj[r * PSTR + u], w_ph[u * NCLS + cls], a);
        out[(size_t)(g * BB + r) * NCLS + cls] = a;
    }
}

extern "C" void kernel_launch(void* const* d_in, const int* in_sizes, int n_in,
                              void* d_out, int out_size, void* d_ws, size_t ws_size,
                              hipStream_t stream)
{
    const float* x    = (const float*)d_in[0];
    const float* w_gx = (const float*)d_in[1];
    const float* w_ix = (const float*)d_in[2];
    const float* w_fx = (const float*)d_in[3];
    const float* w_ox = (const float*)d_in[4];
    const float* w_gh = (const float*)d_in[5];
    const float* w_ih = (const float*)d_in[6];
    const float* w_fh = (const float*)d_in[7];
    const float* w_oh = (const float*)d_in[8];
    const float* b_g  = (const float*)d_in[9];
    const float* b_i  = (const float*)d_in[10];
    const float* b_f  = (const float*)d_in[11];
    const float* b_o  = (const float*)d_in[12];
    const float* w_ph = (const float*)d_in[13];
    const float* b_p  = (const float*)d_in[14];

    signed char* wq8 = (signed char*)d_ws;   // 4*256*256 = 256 KB

    hipLaunchKernelGGL(pack_w, dim3(1024), dim3(64), 0, stream,
                       w_gh, w_ih, w_fh, w_oh, wq8);

    hipLaunchKernelGGL(lstm_full, dim3(NBLOCKS), dim3(NTHR), 0, stream,
                       x, w_gx, w_ix, w_fx, w_ox,
                       b_g, b_i, b_f, b_o, w_ph, b_p,
                       wq8, (float*)d_out);
}